// Round 7
// baseline (576.297 us; speedup 1.0000x reference)
//
#include <hip/hip_runtime.h>
#include <hip/hip_fp16.h>
#include <math.h>

#define NE 16
#define HD 1024
#define FD 2048

// ws layout (4-byte units)
#define TOPI_OFF 0          // 256 int
#define TOPW_OFF 256        // 256 float
#define CNT_OFF  512        // 16 int
#define PREF_OFF 528        // 16 int
#define SLOT_OFF 544        // 256 int (pair -> slot)
#define INVT_OFF 800        // 256 int (slot -> token)
#define HT_OFF   4096       // hT fp16 [2048][256] = 262144 ints
#define Y_OFF    (HT_OFF + 262144)   // y f32 [256][1024]

// fp4 e2m1 nibble -> f32 bits
__device__ __forceinline__ int fp4f(int nib) {
    int c = nib & 7;
    int v = (c == 0) ? 0 : ((c == 1) ? 0x3F000000 : ((((c >> 1) + 126) << 23) | ((c & 1) << 22)));
    return v | ((nib & 8) << 28);
}

__global__ void routing_kernel(const float* __restrict__ x, const float* __restrict__ rw,
                               int* __restrict__ top_idx, float* __restrict__ top_w) {
    int t = blockIdx.x;
    int tid = threadIdx.x;          // 256
    int e = tid >> 4, seg = tid & 15;
    const float* xr = x + t * HD + seg * 64;
    const float* wr = rw + e * HD + seg * 64;
    float p = 0.f;
    #pragma unroll 8
    for (int i = 0; i < 64; ++i) p += xr[i] * wr[i];
    __shared__ float part[16][16];
    __shared__ float logit[16];
    part[e][seg] = p;
    __syncthreads();
    if (tid < 16) {
        float s = 0.f;
        #pragma unroll
        for (int i = 0; i < 16; ++i) s += part[tid][i];
        logit[tid] = s;
    }
    __syncthreads();
    if (tid == 0) {
        int i0 = 0; float v0 = logit[0];
        #pragma unroll
        for (int i = 1; i < 16; ++i) { if (logit[i] > v0) { v0 = logit[i]; i0 = i; } }
        int i1 = -1; float v1 = -1e30f;
        #pragma unroll
        for (int i = 0; i < 16; ++i) { if (i != i0 && logit[i] > v1) { v1 = logit[i]; i1 = i; } }
        float w0 = 1.f / (1.f + expf(v1 - v0));
        float w1 = 1.f / (1.f + expf(v0 - v1));
        top_idx[t * 2]     = i0;  top_w[t * 2]     = w0;
        top_idx[t * 2 + 1] = i1;  top_w[t * 2 + 1] = w1;
    }
}

__global__ void build_kernel(const int* __restrict__ top_idx,
                             int* __restrict__ cnt, int* __restrict__ pref,
                             int* __restrict__ slot, int* __restrict__ invtok) {
    __shared__ int scnt[16], spref[16], scur[16];
    int tid = threadIdx.x;          // 256
    if (tid < 16) scnt[tid] = 0;
    __syncthreads();
    int e = top_idx[tid];
    atomicAdd(&scnt[e], 1);
    __syncthreads();
    if (tid == 0) {
        int s = 0;
        for (int i = 0; i < 16; ++i) { spref[i] = s; pref[i] = s; cnt[i] = scnt[i]; s += scnt[i]; }
    }
    if (tid < 16) scur[tid] = 0;
    __syncthreads();
    int pos = spref[e] + atomicAdd(&scur[e], 1);
    slot[tid] = pos;
    invtok[pos] = tid >> 1;
}

#define FMA16(wk, XP) { \
    float4 xa = XP[0], xb = XP[1], xc = XP[2], xd = XP[3]; \
    acc[0]=fmaf(wk,xa.x,acc[0]); acc[1]=fmaf(wk,xa.y,acc[1]); acc[2]=fmaf(wk,xa.z,acc[2]); acc[3]=fmaf(wk,xa.w,acc[3]); \
    acc[4]=fmaf(wk,xb.x,acc[4]); acc[5]=fmaf(wk,xb.y,acc[5]); acc[6]=fmaf(wk,xb.z,acc[6]); acc[7]=fmaf(wk,xb.w,acc[7]); \
    acc[8]=fmaf(wk,xc.x,acc[8]); acc[9]=fmaf(wk,xc.y,acc[9]); acc[10]=fmaf(wk,xc.z,acc[10]); acc[11]=fmaf(wk,xc.w,acc[11]); \
    acc[12]=fmaf(wk,xd.x,acc[12]); acc[13]=fmaf(wk,xd.y,acc[13]); acc[14]=fmaf(wk,xd.z,acc[14]); acc[15]=fmaf(wk,xd.w,acc[15]); }

// gu GEMM + SwiGLU. Block = 4 waves (K-split 4). Lane = weight row: lane<32 gate f0+lane,
// lane>=32 up f0+lane-32. 16 token-accumulators per lane; x transposed in LDS [k][16].
__global__ __launch_bounds__(256) void gemm1_tile(
    const float* __restrict__ x, const int* __restrict__ qblk,
    const int* __restrict__ qscl, const float* __restrict__ bias,
    const int* __restrict__ cnt, const int* __restrict__ pref,
    const int* __restrict__ invtok, _Float16* __restrict__ hT) {
    int e  = blockIdx.x >> 9;          // 64 fb x 8 mt
    int fb = (blockIdx.x >> 3) & 63;
    int mt = blockIdx.x & 7;
    int n = cnt[e];
    if (mt * 16 >= n) return;
    int base = pref[e];
    int t0 = base + mt * 16;

    __shared__ float xt[1024][16];     // 64 KB; reused as reduce buffer
    __shared__ float2 lut[256];        // 2 KB
    int tid = threadIdx.x;
    lut[tid] = make_float2(__int_as_float(fp4f(tid & 15)), __int_as_float(fp4f(tid >> 4)));

    // stage x transposed: thread (t=tid&15, kc=tid>>4) covers 64 k
    {
        int t = tid & 15, kc = tid >> 4;
        int sl = t0 + t; int smax = base + n - 1;
        if (sl > smax) sl = smax;
        int tok = invtok[sl];
        const float4* xr = (const float4*)(x + (long)tok * HD + kc * 64);
        #pragma unroll
        for (int j = 0; j < 16; ++j) {
            float4 v = xr[j];
            int k = kc * 64 + j * 4;
            xt[k][t] = v.x; xt[k+1][t] = v.y; xt[k+2][t] = v.z; xt[k+3][t] = v.w;
        }
    }
    __syncthreads();

    int wv = tid >> 6, lane = tid & 63;
    int f0 = fb * 32;
    int rowid = (lane < 32) ? (f0 + lane) : (FD + f0 + (lane - 32));
    long rbase = (long)e * 4096 + rowid;
    const int4* wp = (const int4*)(qblk + rbase * 512) + wv * 32;   // 32 int4 = 256 elems
    float scl[8];
    {
        const int4* sp = (const int4*)(qscl + rbase * 32) + wv * 2;
        int4 s0 = sp[0], s1 = sp[1];
        scl[0]=__int_as_float(s0.x<<23); scl[1]=__int_as_float(s0.y<<23);
        scl[2]=__int_as_float(s0.z<<23); scl[3]=__int_as_float(s0.w<<23);
        scl[4]=__int_as_float(s1.x<<23); scl[5]=__int_as_float(s1.y<<23);
        scl[6]=__int_as_float(s1.z<<23); scl[7]=__int_as_float(s1.w<<23);
    }
    int kbase = wv * 256;
    float acc[16];
    #pragma unroll
    for (int i = 0; i < 16; ++i) acc[i] = 0.f;

    #pragma unroll 2
    for (int c = 0; c < 32; ++c) {
        int4 pw = wp[c];
        float s = scl[c >> 2];
        float2 da = lut[pw.x & 255], db = lut[pw.y & 255];
        float2 dc = lut[pw.z & 255], dd = lut[pw.w & 255];
        float w0=da.x*s, w1=da.y*s, w2=db.x*s, w3=db.y*s;
        float w4=dc.x*s, w5=dc.y*s, w6=dd.x*s, w7=dd.y*s;
        const float4* xp;
        int k = kbase + c * 8;
        xp=(const float4*)&xt[k  ][0]; FMA16(w0, xp);
        xp=(const float4*)&xt[k+1][0]; FMA16(w1, xp);
        xp=(const float4*)&xt[k+2][0]; FMA16(w2, xp);
        xp=(const float4*)&xt[k+3][0]; FMA16(w3, xp);
        xp=(const float4*)&xt[k+4][0]; FMA16(w4, xp);
        xp=(const float4*)&xt[k+5][0]; FMA16(w5, xp);
        xp=(const float4*)&xt[k+6][0]; FMA16(w6, xp);
        xp=(const float4*)&xt[k+7][0]; FMA16(w7, xp);
    }
    __syncthreads();                   // x no longer needed; reuse as reduce buf
    float (*red)[64][16] = (float (*)[64][16])xt;
    #pragma unroll
    for (int i = 0; i < 16; ++i) red[wv][lane][i] = acc[i];
    __syncthreads();

    // epilogue: 512 outputs (32 f x 16 t), 2 per thread
    int rl = tid >> 3;                 // 0..31
    int tp = (tid & 7) * 2;
    float bg = bias[(long)e * 4096 + f0 + rl];
    float bu = bias[(long)e * 4096 + FD + f0 + rl];
    #pragma unroll
    for (int d = 0; d < 2; ++d) {
        int tt = tp + d;
        float g = red[0][rl][tt] + red[1][rl][tt] + red[2][rl][tt] + red[3][rl][tt] + bg;
        float u = red[0][rl+32][tt] + red[1][rl+32][tt] + red[2][rl+32][tt] + red[3][rl+32][tt] + bu;
        float h = (g / (1.f + expf(-g))) * u;
        if (mt * 16 + tt < n)
            hT[(long)(f0 + rl) * 256 + t0 + tt] = (_Float16)(h * 0.0625f);  // 2^-4 exact
    }
}

// down GEMM. Block = 8 waves (512 thr), K=2048 in 2 phases of 1024; wave K-slice 128/phase.
__global__ __launch_bounds__(512) void gemm2_tile(
    const _Float16* __restrict__ hT, const int* __restrict__ qblk,
    const int* __restrict__ qscl, const float* __restrict__ bias,
    const int* __restrict__ cnt, const int* __restrict__ pref,
    float* __restrict__ y) {
    int e  = blockIdx.x >> 7;          // 16 hb x 8 mt
    int hb = (blockIdx.x >> 3) & 15;
    int mt = blockIdx.x & 7;
    int n = cnt[e];
    if (mt * 16 >= n) return;
    int base = pref[e];
    int t0 = base + mt * 16;

    __shared__ float xt[1024][16];     // 64 KB per phase; reused as reduce buffer
    __shared__ float2 lut[256];
    int tid = threadIdx.x;
    if (tid < 256)
        lut[tid] = make_float2(__int_as_float(fp4f(tid & 15)), __int_as_float(fp4f(tid >> 4)));

    int wv = tid >> 6, lane = tid & 63;
    int h0 = hb * 64;
    long rbase = (long)e * HD + h0 + lane;
    const int4* wp = (const int4*)(qblk + rbase * 1024);
    const int* sp = qscl + rbase * 64;
    int stt = tid & 15, skc = tid >> 4;          // stage mapping: slot, 32-k group
    int sl = t0 + stt; int smax = base + n - 1;
    if (sl > smax) sl = smax;

    float acc[16];
    #pragma unroll
    for (int i = 0; i < 16; ++i) acc[i] = 0.f;

    for (int ph = 0; ph < 2; ++ph) {
        __syncthreads();
        #pragma unroll 4
        for (int j = 0; j < 32; ++j) {
            int k = skc * 32 + j;
            xt[k][stt] = (float)hT[(long)(ph * 1024 + k) * 256 + sl];
        }
        __syncthreads();
        const int4* wpp = wp + ph * 128 + wv * 16;       // 16 int4 = 128 elems
        int4 sv = *(const int4*)(sp + ph * 32 + wv * 4);
        float scl[4] = { __int_as_float(sv.x<<23), __int_as_float(sv.y<<23),
                         __int_as_float(sv.z<<23), __int_as_float(sv.w<<23) };
        int kbase = wv * 128;
        #pragma unroll 2
        for (int c = 0; c < 16; ++c) {
            int4 pw = wpp[c];
            float s = scl[c >> 2];
            float2 da = lut[pw.x & 255], db = lut[pw.y & 255];
            float2 dc = lut[pw.z & 255], dd = lut[pw.w & 255];
            float w0=da.x*s, w1=da.y*s, w2=db.x*s, w3=db.y*s;
            float w4=dc.x*s, w5=dc.y*s, w6=dd.x*s, w7=dd.y*s;
            const float4* xp;
            int k = kbase + c * 8;
            xp=(const float4*)&xt[k  ][0]; FMA16(w0, xp);
            xp=(const float4*)&xt[k+1][0]; FMA16(w1, xp);
            xp=(const float4*)&xt[k+2][0]; FMA16(w2, xp);
            xp=(const float4*)&xt[k+3][0]; FMA16(w3, xp);
            xp=(const float4*)&xt[k+4][0]; FMA16(w4, xp);
            xp=(const float4*)&xt[k+5][0]; FMA16(w5, xp);
            xp=(const float4*)&xt[k+6][0]; FMA16(w6, xp);
            xp=(const float4*)&xt[k+7][0]; FMA16(w7, xp);
        }
    }
    __syncthreads();
    float (*red)[64][16] = (float (*)[64][16])xt;   // [8][64][16] = 32 KB
    #pragma unroll
    for (int i = 0; i < 16; ++i) red[wv][lane][i] = acc[i];
    __syncthreads();

    int rl = tid >> 3;                 // 0..63
    int tp = (tid & 7) * 2;
    float bv = bias[(long)e * HD + h0 + rl];
    #pragma unroll
    for (int d = 0; d < 2; ++d) {
        int tt = tp + d;
        float a = red[0][rl][tt] + red[1][rl][tt] + red[2][rl][tt] + red[3][rl][tt]
                + red[4][rl][tt] + red[5][rl][tt] + red[6][rl][tt] + red[7][rl][tt];
        if (mt * 16 + tt < n)
            y[(long)(t0 + tt) * HD + h0 + rl] = a * 16.f + bv;
    }
}

__global__ void combine_kernel(const float* __restrict__ ybuf, const int* __restrict__ slot,
                               const float* __restrict__ topw, float* __restrict__ out) {
    int t = blockIdx.x;
    int i = threadIdx.x;   // 256, float4 each
    int s0 = slot[2 * t], s1 = slot[2 * t + 1];
    float w0 = topw[2 * t], w1 = topw[2 * t + 1];
    float4 a = ((const float4*)(ybuf + (long)s0 * HD))[i];
    float4 b = ((const float4*)(ybuf + (long)s1 * HD))[i];
    float4 o;
    o.x = w0 * a.x + w1 * b.x;
    o.y = w0 * a.y + w1 * b.y;
    o.z = w0 * a.z + w1 * b.z;
    o.w = w0 * a.w + w1 * b.w;
    ((float4*)(out + (long)t * HD))[i] = o;
}

extern "C" void kernel_launch(void* const* d_in, const int* in_sizes, int n_in,
                              void* d_out, int out_size, void* d_ws, size_t ws_size,
                              hipStream_t stream) {
    const float* x          = (const float*)d_in[0];
    const float* rw         = (const float*)d_in[1];
    const float* bias_gu    = (const float*)d_in[2];
    const float* bias_down  = (const float*)d_in[3];
    const int*   blocks_gu  = (const int*)d_in[4];
    const int*   scales_gu  = (const int*)d_in[5];
    const int*   blocks_down= (const int*)d_in[6];
    const int*   scales_down= (const int*)d_in[7];
    float* out = (float*)d_out;
    int*   wsI = (int*)d_ws;
    float* wsF = (float*)d_ws;
    _Float16* hT = (_Float16*)(wsI + HT_OFF);
    float*    y  = wsF + Y_OFF;

    routing_kernel<<<128, 256, 0, stream>>>(x, rw, wsI + TOPI_OFF, wsF + TOPW_OFF);
    build_kernel<<<1, 256, 0, stream>>>(wsI + TOPI_OFF, wsI + CNT_OFF, wsI + PREF_OFF,
                                        wsI + SLOT_OFF, wsI + INVT_OFF);
    gemm1_tile<<<NE * 64 * 8, 256, 0, stream>>>(x, blocks_gu, scales_gu, bias_gu,
                                                wsI + CNT_OFF, wsI + PREF_OFF,
                                                wsI + INVT_OFF, hT);
    gemm2_tile<<<NE * 16 * 8, 512, 0, stream>>>(hT, blocks_down, scales_down, bias_down,
                                                wsI + CNT_OFF, wsI + PREF_OFF, y);
    combine_kernel<<<128, 256, 0, stream>>>(y, wsI + SLOT_OFF, wsF + TOPW_OFF, out);
}

// Round 8
// 108.160 us; speedup vs baseline: 5.3282x; 5.3282x over previous
//
#include <hip/hip_runtime.h>
#include <hip/hip_fp16.h>
#include <math.h>

#define NE 16
#define HD 1024
#define FD 2048

typedef _Float16 half2v __attribute__((ext_vector_type(2)));

// ws layout (4-byte units)
#define TOPI_OFF 0          // 256 int
#define TOPW_OFF 256        // 256 float
#define CNT_OFF  512        // 16 int
#define PREF_OFF 528        // 16 int
#define SLOT_OFF 544        // 256 int (pair -> slot)
#define INVT_OFF 800        // 256 int (slot -> token)
#define XH_OFF   4096                   // xh fp16 [256][1024] = 131072 ints
#define HBUF_OFF (XH_OFF + 131072)      // h  fp16 [256][2048] = 262144 ints
#define Y_OFF    (HBUF_OFF + 262144)    // y  f32  [256][1024]

#if __has_builtin(__builtin_amdgcn_fdot2)
#define FDOT2(a, b, c) __builtin_amdgcn_fdot2(a, b, c, false)
#else
__device__ __forceinline__ float FDOT2(half2v a, half2v b, float c) {
    return fmaf((float)a.x, (float)b.x, fmaf((float)a.y, (float)b.y, c));
}
#endif

// fp4 e2m1 nibble -> fp16 bits (unscaled)
__device__ __forceinline__ int fp4h(int nib) {
    int c = nib & 7;
    int v;
    if (c == 0) v = 0;
    else if (c == 1) v = 14 << 10;                        // 0.5
    else v = (((c >> 1) + 14) << 10) | ((c & 1) << 9);
    v |= (nib & 8) << 12;
    return v;
}

// LUT byte -> 2 packed fp16 times packed pow2 scale (exact)
__device__ __forceinline__ half2v dec2(const int* lut, int byte, int sv) {
    int l = lut[byte & 255];
    __half2 p = *reinterpret_cast<const __half2*>(&l);
    __half2 sc = *reinterpret_cast<const __half2*>(&sv);
    __half2 r = __hmul2(p, sc);
    return *reinterpret_cast<half2v*>(&r);
}

__global__ void routing_kernel(const float* __restrict__ x, const float* __restrict__ rw,
                               int* __restrict__ top_idx, float* __restrict__ top_w) {
    int t = blockIdx.x;
    int tid = threadIdx.x;          // 256
    int e = tid >> 4, seg = tid & 15;
    const float* xr = x + t * HD + seg * 64;
    const float* wr = rw + e * HD + seg * 64;
    float p = 0.f;
    #pragma unroll 8
    for (int i = 0; i < 64; ++i) p += xr[i] * wr[i];
    __shared__ float part[16][16];
    __shared__ float logit[16];
    part[e][seg] = p;
    __syncthreads();
    if (tid < 16) {
        float s = 0.f;
        #pragma unroll
        for (int i = 0; i < 16; ++i) s += part[tid][i];
        logit[tid] = s;
    }
    __syncthreads();
    if (tid == 0) {
        int i0 = 0; float v0 = logit[0];
        #pragma unroll
        for (int i = 1; i < 16; ++i) { if (logit[i] > v0) { v0 = logit[i]; i0 = i; } }
        int i1 = -1; float v1 = -1e30f;
        #pragma unroll
        for (int i = 0; i < 16; ++i) { if (i != i0 && logit[i] > v1) { v1 = logit[i]; i1 = i; } }
        float w0 = 1.f / (1.f + expf(v1 - v0));
        float w1 = 1.f / (1.f + expf(v0 - v1));
        top_idx[t * 2]     = i0;  top_w[t * 2]     = w0;
        top_idx[t * 2 + 1] = i1;  top_w[t * 2 + 1] = w1;
    }
}

__global__ void build_kernel(const int* __restrict__ top_idx,
                             int* __restrict__ cnt, int* __restrict__ pref,
                             int* __restrict__ slot, int* __restrict__ invtok) {
    __shared__ int scnt[16], spref[16], scur[16];
    int tid = threadIdx.x;          // 256
    if (tid < 16) scnt[tid] = 0;
    __syncthreads();
    int e = top_idx[tid];
    atomicAdd(&scnt[e], 1);
    __syncthreads();
    if (tid == 0) {
        int s = 0;
        for (int i = 0; i < 16; ++i) { spref[i] = s; pref[i] = s; cnt[i] = scnt[i]; s += scnt[i]; }
    }
    if (tid < 16) scur[tid] = 0;
    __syncthreads();
    int pos = spref[e] + atomicAdd(&scur[e], 1);
    slot[tid] = pos;
    invtok[pos] = tid >> 1;
}

__global__ void gather_kernel(const float* __restrict__ x, const int* __restrict__ invtok,
                              _Float16* __restrict__ xh) {
    int slt = blockIdx.x;           // 256
    int t = invtok[slt];
    int i = threadIdx.x;            // 256 threads x 4 elems
    float4 v = ((const float4*)(x + (long)t * HD))[i];
    union { _Float16 h[4]; int2 p; } o;
    o.h[0] = (_Float16)v.x; o.h[1] = (_Float16)v.y;
    o.h[2] = (_Float16)v.z; o.h[3] = (_Float16)v.w;
    ((int2*)(xh + (long)slt * HD))[i] = o.p;
}

// gu GEMM + SwiGLU. Wave owns 2 f (rows g0,g1,u0,u1). Lane covers k=16*lane..+15
// (2 coalesced int4 weight loads/row, 2 int4 fp16 x loads/token). fdot2 accumulate.
__global__ __launch_bounds__(256, 4) void gemm1_dot(
    const _Float16* __restrict__ xh, const int* __restrict__ qblk,
    const int* __restrict__ qscl, const float* __restrict__ bias,
    const int* __restrict__ cnt, const int* __restrict__ pref,
    _Float16* __restrict__ hbuf) {
    int e = blockIdx.x >> 8;        // 256 blocks/expert (8 f each)
    int fb = blockIdx.x & 255;
    int n = cnt[e];
    if (n == 0) return;
    __shared__ int lut[256];
    int tid = threadIdx.x;
    lut[tid] = fp4h(tid & 15) | (fp4h(tid >> 4) << 16);
    __syncthreads();
    int wave = tid >> 6, lane = tid & 63;
    int f0 = fb * 8 + wave * 2;
    long rg0 = (long)e * 4096 + f0;

    half2v w[4][8];
    #pragma unroll
    for (int r = 0; r < 4; ++r) {
        long row = rg0 + (r & 1) + ((r & 2) ? FD : 0);
        int sc = qscl[row * 32 + (lane >> 1)];
        int sv = (sc - 112) << 10; sv |= sv << 16;
        const int4* wp = (const int4*)(qblk + row * 512) + lane * 2;
        int4 q0 = wp[0], q1 = wp[1];
        w[r][0] = dec2(lut, q0.x, sv); w[r][1] = dec2(lut, q0.y, sv);
        w[r][2] = dec2(lut, q0.z, sv); w[r][3] = dec2(lut, q0.w, sv);
        w[r][4] = dec2(lut, q1.x, sv); w[r][5] = dec2(lut, q1.y, sv);
        w[r][6] = dec2(lut, q1.z, sv); w[r][7] = dec2(lut, q1.w, sv);
    }
    float bg = bias[rg0 + (lane >> 5)];
    float ub = bias[rg0 + FD + (lane >> 5)];
    int base = pref[e];

    for (int j = 0; j < n; ++j) {
        const int4* xr = (const int4*)(xh + (long)(base + j) * HD) + lane * 2;
        union { int4 v; half2v h[4]; } xa, xb;
        xa.v = xr[0]; xb.v = xr[1];
        float a0=0,a1=0,a2=0,a3=0,a4=0,a5=0,a6=0,a7=0;
        #pragma unroll
        for (int i = 0; i < 4; ++i) {
            a0 = FDOT2(w[0][i],   xa.h[i], a0);
            a1 = FDOT2(w[0][i+4], xb.h[i], a1);
            a2 = FDOT2(w[1][i],   xa.h[i], a2);
            a3 = FDOT2(w[1][i+4], xb.h[i], a3);
            a4 = FDOT2(w[2][i],   xa.h[i], a4);
            a5 = FDOT2(w[2][i+4], xb.h[i], a5);
            a6 = FDOT2(w[3][i],   xa.h[i], a6);
            a7 = FDOT2(w[3][i+4], xb.h[i], a7);
        }
        float g0 = a0 + a1, g1 = a2 + a3, u0 = a4 + a5, u1 = a6 + a7;
        // paired-merge butterfly: 4 values reduced, totals land on lanes 0/16/32/48
        float s = __shfl_xor(g0, 32), t2 = __shfl_xor(g1, 32);
        float cg = (lane & 32) ? (g1 + t2) : (g0 + s);
        s = __shfl_xor(u0, 32); t2 = __shfl_xor(u1, 32);
        float cu = (lane & 32) ? (u1 + t2) : (u0 + s);
        s = __shfl_xor(cg, 16); t2 = __shfl_xor(cu, 16);
        float cc = (lane & 16) ? (cu + t2) : (cg + s);
        cc += __shfl_xor(cc, 8); cc += __shfl_xor(cc, 4);
        cc += __shfl_xor(cc, 2); cc += __shfl_xor(cc, 1);
        float other = __shfl_xor(cc, 16);     // lane0 <- u0 total, lane32 <- u1 total
        if ((lane & 31) == 0) {
            float g = cc + bg;
            float u = other + ub;
            float h = (g / (1.f + expf(-g))) * u;
            hbuf[(long)(base + j) * FD + f0 + (lane >> 5)] = (_Float16)(h * 0.0625f); // 2^-4
        }
    }
}

// down GEMM. Wave owns 2 h rows; lane covers k=32*lane..+31 (4 int4 weight loads/row).
__global__ __launch_bounds__(256, 4) void gemm2_dot(
    const _Float16* __restrict__ hbuf, const int* __restrict__ qblk,
    const int* __restrict__ qscl, const float* __restrict__ bias,
    const int* __restrict__ cnt, const int* __restrict__ pref,
    float* __restrict__ y) {
    int e = blockIdx.x >> 7;        // 128 blocks/expert (8 h each)
    int hb = blockIdx.x & 127;
    int n = cnt[e];
    if (n == 0) return;
    __shared__ int lut[256];
    int tid = threadIdx.x;
    lut[tid] = fp4h(tid & 15) | (fp4h(tid >> 4) << 16);
    __syncthreads();
    int wave = tid >> 6, lane = tid & 63;
    int h0 = hb * 8 + wave * 2;
    long r0 = (long)e * HD + h0;

    half2v w[2][16];
    #pragma unroll
    for (int r = 0; r < 2; ++r) {
        long row = r0 + r;
        int sc = qscl[row * 64 + lane];
        int sv = (sc - 112) << 10; sv |= sv << 16;
        const int4* wp = (const int4*)(qblk + row * 1024) + lane * 4;
        #pragma unroll
        for (int q = 0; q < 4; ++q) {
            int4 qq = wp[q];
            w[r][q*4+0] = dec2(lut, qq.x, sv);
            w[r][q*4+1] = dec2(lut, qq.y, sv);
            w[r][q*4+2] = dec2(lut, qq.z, sv);
            w[r][q*4+3] = dec2(lut, qq.w, sv);
        }
    }
    float bv = bias[r0 + (lane >> 5)];
    int base = pref[e];

    for (int j = 0; j < n; ++j) {
        const int4* hr = (const int4*)(hbuf + (long)(base + j) * FD) + lane * 4;
        float a0=0, a1=0, b0=0, b1=0;
        #pragma unroll
        for (int q = 0; q < 4; ++q) {
            union { int4 v; half2v h[4]; } xq;
            xq.v = hr[q];
            a0 = FDOT2(w[0][q*4+0], xq.h[0], a0);
            a1 = FDOT2(w[0][q*4+1], xq.h[1], a1);
            a0 = FDOT2(w[0][q*4+2], xq.h[2], a0);
            a1 = FDOT2(w[0][q*4+3], xq.h[3], a1);
            b0 = FDOT2(w[1][q*4+0], xq.h[0], b0);
            b1 = FDOT2(w[1][q*4+1], xq.h[1], b1);
            b0 = FDOT2(w[1][q*4+2], xq.h[2], b0);
            b1 = FDOT2(w[1][q*4+3], xq.h[3], b1);
        }
        float A = a0 + a1, B = b0 + b1;
        float s = __shfl_xor(A, 32), t2 = __shfl_xor(B, 32);
        float ca = (lane & 32) ? (B + t2) : (A + s);
        ca += __shfl_xor(ca, 16); ca += __shfl_xor(ca, 8);
        ca += __shfl_xor(ca, 4);  ca += __shfl_xor(ca, 2);
        ca += __shfl_xor(ca, 1);
        if ((lane & 31) == 0)
            y[(long)(base + j) * HD + h0 + (lane >> 5)] = ca * 16.f + bv;
    }
}

__global__ void combine_kernel(const float* __restrict__ ybuf, const int* __restrict__ slot,
                               const float* __restrict__ topw, float* __restrict__ out) {
    int t = blockIdx.x;
    int i = threadIdx.x;   // 256, float4 each
    int s0 = slot[2 * t], s1 = slot[2 * t + 1];
    float w0 = topw[2 * t], w1 = topw[2 * t + 1];
    float4 a = ((const float4*)(ybuf + (long)s0 * HD))[i];
    float4 b = ((const float4*)(ybuf + (long)s1 * HD))[i];
    float4 o;
    o.x = w0 * a.x + w1 * b.x;
    o.y = w0 * a.y + w1 * b.y;
    o.z = w0 * a.z + w1 * b.z;
    o.w = w0 * a.w + w1 * b.w;
    ((float4*)(out + (long)t * HD))[i] = o;
}

extern "C" void kernel_launch(void* const* d_in, const int* in_sizes, int n_in,
                              void* d_out, int out_size, void* d_ws, size_t ws_size,
                              hipStream_t stream) {
    const float* x          = (const float*)d_in[0];
    const float* rw         = (const float*)d_in[1];
    const float* bias_gu    = (const float*)d_in[2];
    const float* bias_down  = (const float*)d_in[3];
    const int*   blocks_gu  = (const int*)d_in[4];
    const int*   scales_gu  = (const int*)d_in[5];
    const int*   blocks_down= (const int*)d_in[6];
    const int*   scales_down= (const int*)d_in[7];
    float* out = (float*)d_out;
    int*   wsI = (int*)d_ws;
    float* wsF = (float*)d_ws;
    _Float16* xh   = (_Float16*)(wsI + XH_OFF);
    _Float16* hbuf = (_Float16*)(wsI + HBUF_OFF);
    float*    y    = wsF + Y_OFF;

    routing_kernel<<<128, 256, 0, stream>>>(x, rw, wsI + TOPI_OFF, wsF + TOPW_OFF);
    build_kernel<<<1, 256, 0, stream>>>(wsI + TOPI_OFF, wsI + CNT_OFF, wsI + PREF_OFF,
                                        wsI + SLOT_OFF, wsI + INVT_OFF);
    gather_kernel<<<256, 256, 0, stream>>>(x, wsI + INVT_OFF, xh);
    gemm1_dot<<<NE * 256, 256, 0, stream>>>(xh, blocks_gu, scales_gu, bias_gu,
                                            wsI + CNT_OFF, wsI + PREF_OFF, hbuf);
    gemm2_dot<<<NE * 128, 256, 0, stream>>>(hbuf, blocks_down, scales_down, bias_down,
                                            wsI + CNT_OFF, wsI + PREF_OFF, y);
    combine_kernel<<<128, 256, 0, stream>>>(y, wsI + SLOT_OFF, wsF + TOPW_OFF, out);
}